// Round 4
// baseline (1157.949 us; speedup 1.0000x reference)
//
#include <hip/hip_runtime.h>
#include <math.h>

// CapsuleRouting: u (8,144,16,16,12,12) f32, a (8,144,12,12) f32
// out: v (8,16,16,144) f32  ++  a_out (8,16,144) f32
//
// Fused structure: 3 dispatches (one per routing iteration). Each block
// computes a softmax-weighted partial sum over its B-chunk, stores it, then
// the LAST-arriving block per (b, posg-tile) group reduces all 18 chunks,
// squashes, and updates V / writes outputs (device-scope last-arriver).
//
// Arrival counters are ZEROED by a tiny (864 B) hipMemsetAsync each launch:
// the harness poisons the workspace between runs, and last-arriver detection
// is only correct when the counter starts at 0 (mod-18 alone picks a
// MID-arriving block when the start value is arbitrary -> race; round-3 bug).
//
// j-loop barriers are raw s_barrier + lgkmcnt(0) only: LDS ordering is fully
// covered (e-visibility and ebuf ping-pong WAR both hang on lgkmcnt), while
// prefetched next-j global loads stay in flight (no vmcnt(0) drain).

#define NB 8
#define BDIM 144
#define CDIM 16
#define PDIM 16
#define SDIM 144
#define PT 16
#define BC 8                              // B per chunk
#define NPT (SDIM / PT)                   // 9
#define NBC (BDIM / BC)                   // 18
#define USTRIDE (CDIM * PDIM * SDIM)      // 36864 floats between consecutive B
#define VELEMS (NB * CDIM * PDIM * SDIM)  // 294912
#define AELEMS (NB * CDIM * SDIM)         // 18432
#define NGROUP (NB * NPT)                 // 72 reduction groups

__global__ __launch_bounds__(256) void route_kernel(
    const float* __restrict__ u, const float* __restrict__ a,
    float* __restrict__ V, float* __restrict__ part,
    unsigned int* __restrict__ cnt,
    float* __restrict__ out_v, float* __restrict__ out_a, int iter) {
  __shared__ float Vt[CDIM][PDIM][PT + 1];  // padded: 4-way -> 2-way (free)
  __shared__ float ebuf[2][CDIM][PT + 1];
  __shared__ float atile[BC][PT];
  __shared__ int isLast;

  const int tid = threadIdx.x;
  const int pos = tid & 15;  // fast -> coalesced (64B runs per 16 lanes)
  const int c = tid >> 4;
  const int chunk = blockIdx.x;
  const int y = blockIdx.y;
  const int b = blockIdx.z;
  const int posg = y * PT + pos;
  const int B0 = chunk * BC;

  const float* ubase =
      u + ((size_t)((b * BDIM + B0) * CDIM + c) * PDIM) * SDIM + posg;

  float sacc[PDIM];
#pragma unroll
  for (int p = 0; p < PDIM; ++p) sacc[p] = 0.f;

  if (iter == 0) {
    // softmax of a constant over C => uniform 1/C: pure streaming sum
#pragma unroll 2
    for (int j = 0; j < BC; ++j) {
      const float* ub = ubase + (size_t)j * USTRIDE;
#pragma unroll
      for (int p = 0; p < PDIM; ++p) sacc[p] += ub[p * SDIM];
    }
#pragma unroll
    for (int p = 0; p < PDIM; ++p) sacc[p] *= (1.0f / CDIM);
  } else {
    float uvbuf[2][PDIM];
#pragma unroll
    for (int p = 0; p < PDIM; ++p) uvbuf[0][p] = ubase[p * SDIM];  // j=0 prologue

    {
      const int vb = ((b * CDIM + c) * PDIM) * SDIM + posg;
#pragma unroll
      for (int p = 0; p < PDIM; ++p) Vt[c][p][pos] = V[vb + p * SDIM];
      if (tid < BC * PT) {
        const int j = tid >> 4;
        atile[j][pos] =
            a[(b * BDIM + B0 + j) * SDIM + y * PT + pos] * (1.0f / CDIM);
      }
    }
    __syncthreads();  // full barrier once (staging)

#pragma unroll
    for (int j = 0; j < BC; ++j) {
      float* uv = uvbuf[j & 1];
      float* uvn = uvbuf[(j + 1) & 1];
      if (j + 1 < BC) {  // issue next-B loads; they survive the raw barrier
        const float* ub = ubase + (size_t)(j + 1) * USTRIDE;
#pragma unroll
        for (int p = 0; p < PDIM; ++p) uvn[p] = ub[p * SDIM];
      }
      float dot = 0.f;
#pragma unroll
      for (int p = 0; p < PDIM; ++p) dot += uv[p] * Vt[c][p][pos];
      const float e = __expf(atile[j][pos] + dot);  // no-max softmax: |logit|~O(10)
      ebuf[j & 1][c][pos] = e;
      // lgkmcnt-only barrier: ds_write visible + previous ebuf reads retired
      // (WAR for the ping-pong), but prefetch vmem NOT drained.
      asm volatile("s_waitcnt lgkmcnt(0)" ::: "memory");
      __builtin_amdgcn_s_barrier();
      float sum = 0.f;
#pragma unroll
      for (int c2 = 0; c2 < CDIM; ++c2) sum += ebuf[j & 1][c2][pos];
      const float w = e * __builtin_amdgcn_rcpf(sum);
#pragma unroll
      for (int p = 0; p < PDIM; ++p) sacc[p] += w * uv[p];
    }
  }

  // partial store (plain stores, no atomics)
  {
    float* sp = part + (size_t)chunk * VELEMS +
                ((b * CDIM + c) * PDIM) * SDIM + posg;
#pragma unroll
    for (int p = 0; p < PDIM; ++p) sp[p * SDIM] = sacc[p];
  }

  // ---- last-arriver reduction ----
  __threadfence();   // release own partial stores (device scope)
  __syncthreads();   // all threads' fences precede the arrival atomic
  if (tid == 0) {
    const unsigned old = atomicAdd(&cnt[iter * NGROUP + b * NPT + y], 1u);
    isLast = (old == (NBC - 1));  // cnt zeroed each launch by host memset
  }
  __syncthreads();
  if (!isLast) return;
  __threadfence();   // acquire side before reading other blocks' partials

  float sv[PDIM];
#pragma unroll
  for (int p = 0; p < PDIM; ++p) sv[p] = 0.f;
  const int base = ((b * CDIM + c) * PDIM) * SDIM + posg;
#pragma unroll 2
  for (int k = 0; k < NBC; ++k) {
    const float* sp = part + (size_t)k * VELEMS + base;
#pragma unroll
    for (int p = 0; p < PDIM; ++p) sv[p] += sp[p * SDIM];
  }
  float sn = 0.f;
#pragma unroll
  for (int p = 0; p < PDIM; ++p) sn += sv[p] * sv[p];
  const float scale = sn / (1.0f + sn) * rsqrtf(sn);

  if (iter == 0) {
#pragma unroll
    for (int p = 0; p < PDIM; ++p) V[base + p * SDIM] = sv[p] * scale;
  } else if (iter == 1) {
#pragma unroll
    for (int p = 0; p < PDIM; ++p) V[base + p * SDIM] += sv[p] * scale;
  } else {
    float vv = 0.f;
#pragma unroll
    for (int p = 0; p < PDIM; ++p) {
      const float v = sv[p] * scale;
      out_v[base + p * SDIM] = v;
      vv += v * v;
    }
    out_a[(b * CDIM + c) * SDIM + posg] = sqrtf(vv);
  }
}

// ---------------- launch: tiny counter memset + 3 kernel dispatches ----------------

extern "C" void kernel_launch(void* const* d_in, const int* in_sizes, int n_in,
                              void* d_out, int out_size, void* d_ws, size_t ws_size,
                              hipStream_t stream) {
  const float* u = (const float*)d_in[0];
  const float* a = (const float*)d_in[1];
  float* out_v = (float*)d_out;
  float* out_a = out_v + VELEMS;

  // ws layout: V [VELEMS] | part [NBC*VELEMS] | cnt [3*NGROUP uints] (~22.4 MB)
  float* V = (float*)d_ws;
  float* part = V + VELEMS;
  unsigned int* cnt = (unsigned int*)(part + (size_t)NBC * VELEMS);

  // Workspace is POISONED by the harness between runs: counters MUST start at 0
  // for last-arriver detection. 864 bytes -> ~2 us dispatch.
  hipMemsetAsync(cnt, 0, 3 * NGROUP * sizeof(unsigned int), stream);

  const dim3 g(NBC, NPT, NB);  // 18 x 9 x 8 = 1296 blocks
  for (int it = 0; it < 3; ++it)
    route_kernel<<<g, 256, 0, stream>>>(u, a, V, part, cnt, out_v, out_a, it);
}

// Round 5
// 358.800 us; speedup vs baseline: 3.2273x; 3.2273x over previous
//
#include <hip/hip_runtime.h>
#include <math.h>

// CapsuleRouting: u (8,144,16,16,12,12) f32, a (8,144,12,12) f32
// out: v (8,16,16,144) f32  ++  a_out (8,16,144) f32
//
// Fused: 3 dispatches (one per routing iteration). Each block computes a
// softmax-weighted partial sum over its B-chunk and accumulates it into the
// per-iteration s-buffer with device-scope atomicAdd (coherence-point RMW,
// NO __threadfence — round-4 counters proved fences cost ~300us/dispatch:
// VALUBusy 0.36%, 1296 blocks x buffer_wbl2 serialized). The LAST-arriving
// block per (b, pos-tile) group (atomic counter) reduces: loads s, squashes,
// updates V / writes outputs. Safety without fences:
//  - vmcnt(0)+barrier before the arrival atomic => this block's adds applied
//  - old==17 => ALL blocks' adds applied (counter RMW is after their drains)
//  - s lines touched only by atomics this dispatch (no stale L1/L2 copies);
//    per-iteration s slice avoids cross-dispatch staleness.
// cnt+s zeroed by one ~3.5MB memset per launch (workspace is poisoned).
//
// j-loop barriers are raw s_barrier + lgkmcnt(0) only: LDS ordering fully
// covered (ebuf visibility + ping-pong WAR hang on lgkmcnt), while prefetched
// next-j global loads stay in flight (no vmcnt(0) drain).

#define NB 8
#define BDIM 144
#define CDIM 16
#define PDIM 16
#define SDIM 144
#define PT 16
#define BC 8                              // B per chunk
#define NPT (SDIM / PT)                   // 9
#define NBC (BDIM / BC)                   // 18
#define USTRIDE (CDIM * PDIM * SDIM)      // 36864 floats between consecutive B
#define VELEMS (NB * CDIM * PDIM * SDIM)  // 294912
#define NGROUP (NB * NPT)                 // 72 reduction groups

__global__ __launch_bounds__(256) void route_kernel(
    const float* __restrict__ u, const float* __restrict__ a,
    float* __restrict__ V, float* __restrict__ s,
    unsigned int* __restrict__ cnt,
    float* __restrict__ out_v, float* __restrict__ out_a, int iter) {
  __shared__ float Vt[CDIM][PDIM][PT + 1];  // padded: 4-way -> 2-way (free)
  __shared__ float ebuf[2][CDIM][PT + 1];
  __shared__ float atile[BC][PT];
  __shared__ int isLast;

  const int tid = threadIdx.x;
  const int pos = tid & 15;  // fast -> coalesced (64B runs per 16 lanes)
  const int c = tid >> 4;
  const int chunk = blockIdx.x;
  const int y = blockIdx.y;
  const int b = blockIdx.z;
  const int posg = y * PT + pos;
  const int B0 = chunk * BC;

  const float* ubase =
      u + ((size_t)((b * BDIM + B0) * CDIM + c) * PDIM) * SDIM + posg;

  float sacc[PDIM];
#pragma unroll
  for (int p = 0; p < PDIM; ++p) sacc[p] = 0.f;

  if (iter == 0) {
    // softmax of a constant over C => uniform 1/C: pure streaming sum
#pragma unroll 2
    for (int j = 0; j < BC; ++j) {
      const float* ub = ubase + (size_t)j * USTRIDE;
#pragma unroll
      for (int p = 0; p < PDIM; ++p) sacc[p] += ub[p * SDIM];
    }
#pragma unroll
    for (int p = 0; p < PDIM; ++p) sacc[p] *= (1.0f / CDIM);
  } else {
    float uvbuf[2][PDIM];
#pragma unroll
    for (int p = 0; p < PDIM; ++p) uvbuf[0][p] = ubase[p * SDIM];  // j=0 prologue

    {
      const int vb = ((b * CDIM + c) * PDIM) * SDIM + posg;
#pragma unroll
      for (int p = 0; p < PDIM; ++p) Vt[c][p][pos] = V[vb + p * SDIM];
      if (tid < BC * PT) {
        const int j = tid >> 4;
        atile[j][pos] =
            a[(b * BDIM + B0 + j) * SDIM + y * PT + pos] * (1.0f / CDIM);
      }
    }
    __syncthreads();  // staging barrier

#pragma unroll
    for (int j = 0; j < BC; ++j) {
      float* uv = uvbuf[j & 1];
      float* uvn = uvbuf[(j + 1) & 1];
      if (j + 1 < BC) {  // issue next-B loads; they survive the raw barrier
        const float* ub = ubase + (size_t)(j + 1) * USTRIDE;
#pragma unroll
        for (int p = 0; p < PDIM; ++p) uvn[p] = ub[p * SDIM];
      }
      float dot = 0.f;
#pragma unroll
      for (int p = 0; p < PDIM; ++p) dot += uv[p] * Vt[c][p][pos];
      const float e = __expf(atile[j][pos] + dot);  // no-max softmax: |logit|~O(10)
      ebuf[j & 1][c][pos] = e;
      // lgkmcnt-only barrier: ds_write visible + prior ebuf reads retired,
      // prefetch vmem NOT drained.
      asm volatile("s_waitcnt lgkmcnt(0)" ::: "memory");
      __builtin_amdgcn_s_barrier();
      float sum = 0.f;
#pragma unroll
      for (int c2 = 0; c2 < CDIM; ++c2) sum += ebuf[j & 1][c2][pos];
      const float w = e * __builtin_amdgcn_rcpf(sum);
#pragma unroll
      for (int p = 0; p < PDIM; ++p) sacc[p] += w * uv[p];
    }
  }

  // accumulate partials at the coherence point (no fences needed)
  const int base = ((b * CDIM + c) * PDIM) * SDIM + posg;
#pragma unroll
  for (int p = 0; p < PDIM; ++p) atomicAdd(&s[base + p * SDIM], sacc[p]);

  // ---- last-arriver detection ----
  asm volatile("s_waitcnt vmcnt(0)" ::: "memory");  // our atomics applied
  __syncthreads();                                  // whole block drained
  if (tid == 0) {
    const unsigned old = atomicAdd(&cnt[b * NPT + y], 1u);
    isLast = (old == (NBC - 1));  // cnt zeroed each launch by host memset
  }
  __syncthreads();
  if (!isLast) return;

  // all 18 chunks' atomics are applied; s lines have no stale local copies
  float sv[PDIM];
  float sn = 0.f;
#pragma unroll
  for (int p = 0; p < PDIM; ++p) {
    const float x = s[base + p * SDIM];
    sv[p] = x;
    sn += x * x;
  }
  const float scale = sn / (1.0f + sn) * rsqrtf(sn);

  if (iter == 0) {
#pragma unroll
    for (int p = 0; p < PDIM; ++p) V[base + p * SDIM] = sv[p] * scale;
  } else if (iter == 1) {
#pragma unroll
    for (int p = 0; p < PDIM; ++p) V[base + p * SDIM] += sv[p] * scale;
  } else {
    float vv = 0.f;
#pragma unroll
    for (int p = 0; p < PDIM; ++p) {
      const float v = sv[p] * scale;
      out_v[base + p * SDIM] = v;
      vv += v * v;
    }
    out_a[(b * CDIM + c) * SDIM + posg] = sqrtf(vv);
  }
}

// ---------------- launch: one small memset + 3 kernel dispatches ----------------

extern "C" void kernel_launch(void* const* d_in, const int* in_sizes, int n_in,
                              void* d_out, int out_size, void* d_ws, size_t ws_size,
                              hipStream_t stream) {
  const float* u = (const float*)d_in[0];
  const float* a = (const float*)d_in[1];
  float* out_v = (float*)d_out;
  float* out_a = out_v + VELEMS;

  // ws layout: V [VELEMS] | s [3*VELEMS] | cnt [3*NGROUP] (~4.7 MB total)
  float* V = (float*)d_ws;
  float* s = V + VELEMS;
  unsigned int* cnt = (unsigned int*)(s + (size_t)3 * VELEMS);

  // zero the atomic accumulators + arrival counters (workspace is poisoned)
  hipMemsetAsync(s, 0, (size_t)3 * VELEMS * sizeof(float) +
                           3 * NGROUP * sizeof(unsigned int), stream);

  const dim3 g(NBC, NPT, NB);  // 18 x 9 x 8 = 1296 blocks
  for (int it = 0; it < 3; ++it)
    route_kernel<<<g, 256, 0, stream>>>(u, a, V, s + (size_t)it * VELEMS,
                                        cnt + it * NGROUP, out_v, out_a, it);
}